// Round 1
// baseline (1282.499 us; speedup 1.0000x reference)
//
#include <hip/hip_runtime.h>

#define VEC_DIM   300
#define NUM_WORDS 100000
#define BATCH_N   4096
#define NUM_CTX   10
#define NUM_NOISE 26

// One block per batch element.
// Phase 1: x = D[doc] + sum_c W[ctx_c]  -> LDS (coalesced 300-float row reads)
// Phase 2: 4 waves x strided n; lanes over d; width-64 shuffle reduction.
__global__ __launch_bounds__(256) void pvdm_score_kernel(
    const int*   __restrict__ context_ids,   // (B, 10)
    const int*   __restrict__ doc_ids,       // (B,)
    const int*   __restrict__ tn_ids,        // (B, 26)
    const float* __restrict__ D,             // (500000, 300)
    const float* __restrict__ W,             // (100000, 300)
    const float* __restrict__ O,             // (300, 100000)
    float*       __restrict__ out)           // (B, 26)
{
    __shared__ float xs[VEC_DIM];
    const int b   = blockIdx.x;
    const int tid = threadIdx.x;

    const int doc = doc_ids[b];
    int ctx[NUM_CTX];
#pragma unroll
    for (int c = 0; c < NUM_CTX; ++c) ctx[c] = context_ids[b * NUM_CTX + c];

    // Phase 1: compute x into LDS. Threads sweep d; consecutive tid ->
    // consecutive addresses within each gathered row (coalesced).
    for (int d = tid; d < VEC_DIM; d += 256) {
        float v = D[(size_t)doc * VEC_DIM + d];
#pragma unroll
        for (int c = 0; c < NUM_CTX; ++c)
            v += W[(size_t)ctx[c] * VEC_DIM + d];
        xs[d] = v;
    }
    __syncthreads();

    // Phase 2: dot(x, O[:, t]) per noise word. O column access is
    // inherently strided (stride = NUM_WORDS floats) — gather-bound.
    const int wave = tid >> 6;
    const int lane = tid & 63;
    for (int n = wave; n < NUM_NOISE; n += 4) {
        const int t = tn_ids[b * NUM_NOISE + n];
        float s = 0.0f;
        for (int d = lane; d < VEC_DIM; d += 64) {
            s += xs[d] * O[(size_t)d * NUM_WORDS + t];
        }
#pragma unroll
        for (int off = 32; off > 0; off >>= 1)
            s += __shfl_down(s, off, 64);
        if (lane == 0) out[b * NUM_NOISE + n] = s;
    }
}

extern "C" void kernel_launch(void* const* d_in, const int* in_sizes, int n_in,
                              void* d_out, int out_size, void* d_ws, size_t ws_size,
                              hipStream_t stream) {
    const int*   context_ids = (const int*)  d_in[0];
    const int*   doc_ids     = (const int*)  d_in[1];
    const int*   tn_ids      = (const int*)  d_in[2];
    const float* D           = (const float*)d_in[3];
    const float* W           = (const float*)d_in[4];
    const float* O           = (const float*)d_in[5];
    float*       out         = (float*)d_out;

    pvdm_score_kernel<<<BATCH_N, 256, 0, stream>>>(
        context_ids, doc_ids, tn_ids, D, W, O, out);
}

// Round 2
// 841.365 us; speedup vs baseline: 1.5243x; 1.5243x over previous
//
#include <hip/hip_runtime.h>

#define VEC_DIM   300
#define NUM_WORDS 100000
#define BATCH_N   4096
#define NUM_CTX   10
#define NUM_NOISE 26
#define TILE      64

// ---------------- Transpose O (300 x 100000) -> OT (100000 x 300) ----------
// 64x64 LDS tile, 256 threads (64 x-threads, 4 y-rows per pass).
// Read coalesced along words; write coalesced along vec-dim.
__global__ __launch_bounds__(256) void transpose_kernel(
    const float* __restrict__ O,   // (300, 100000)
    float*       __restrict__ OT)  // (100000, 300)
{
    __shared__ float tile[TILE][TILE + 1];  // +1 pad: lanes hit banks stride-65 -> conflict-free
    const int wBase = blockIdx.x * TILE;    // word dim
    const int dBase = blockIdx.y * TILE;    // vec dim
    const int tx = threadIdx.x & (TILE - 1);
    const int ty = threadIdx.x >> 6;        // 0..3

    const int w_in = wBase + tx;
#pragma unroll
    for (int j = 0; j < TILE; j += 4) {
        const int d = dBase + ty + j;
        if (d < VEC_DIM && w_in < NUM_WORDS)
            tile[ty + j][tx] = O[(size_t)d * NUM_WORDS + w_in];
    }
    __syncthreads();

    const int d_out = dBase + tx;
#pragma unroll
    for (int j = 0; j < TILE; j += 4) {
        const int w = wBase + ty + j;
        if (w < NUM_WORDS && d_out < VEC_DIM)
            OT[(size_t)w * VEC_DIM + d_out] = tile[tx][ty + j];
    }
}

// ---------------- Score kernel: gathers rows of OT (coalesced) -------------
__global__ __launch_bounds__(256) void pvdm_score_kernel(
    const int*   __restrict__ context_ids,   // (B, 10)
    const int*   __restrict__ doc_ids,       // (B,)
    const int*   __restrict__ tn_ids,        // (B, 26)
    const float* __restrict__ D,             // (500000, 300)
    const float* __restrict__ W,             // (100000, 300)
    const float* __restrict__ OT,            // (100000, 300)
    float*       __restrict__ out)           // (B, 26)
{
    __shared__ float xs[VEC_DIM];
    const int b   = blockIdx.x;
    const int tid = threadIdx.x;

    const int doc = doc_ids[b];
    int ctx[NUM_CTX];
#pragma unroll
    for (int c = 0; c < NUM_CTX; ++c) ctx[c] = context_ids[b * NUM_CTX + c];

    for (int d = tid; d < VEC_DIM; d += 256) {
        float v = D[(size_t)doc * VEC_DIM + d];
#pragma unroll
        for (int c = 0; c < NUM_CTX; ++c)
            v += W[(size_t)ctx[c] * VEC_DIM + d];
        xs[d] = v;
    }
    __syncthreads();

    const int wave = tid >> 6;
    const int lane = tid & 63;
    for (int n = wave; n < NUM_NOISE; n += 4) {
        const int t = tn_ids[b * NUM_NOISE + n];
        const float* row = OT + (size_t)t * VEC_DIM;
        float s = 0.0f;
        for (int d = lane; d < VEC_DIM; d += 64)   // coalesced 256 B / wave-load
            s += xs[d] * row[d];
#pragma unroll
        for (int off = 32; off > 0; off >>= 1)
            s += __shfl_down(s, off, 64);
        if (lane == 0) out[b * NUM_NOISE + n] = s;
    }
}

// ---------------- Fallback (direct column gather) if ws too small ----------
__global__ __launch_bounds__(256) void pvdm_score_direct_kernel(
    const int*   __restrict__ context_ids,
    const int*   __restrict__ doc_ids,
    const int*   __restrict__ tn_ids,
    const float* __restrict__ D,
    const float* __restrict__ W,
    const float* __restrict__ O,             // (300, 100000)
    float*       __restrict__ out)
{
    __shared__ float xs[VEC_DIM];
    const int b   = blockIdx.x;
    const int tid = threadIdx.x;
    const int doc = doc_ids[b];
    int ctx[NUM_CTX];
#pragma unroll
    for (int c = 0; c < NUM_CTX; ++c) ctx[c] = context_ids[b * NUM_CTX + c];
    for (int d = tid; d < VEC_DIM; d += 256) {
        float v = D[(size_t)doc * VEC_DIM + d];
#pragma unroll
        for (int c = 0; c < NUM_CTX; ++c)
            v += W[(size_t)ctx[c] * VEC_DIM + d];
        xs[d] = v;
    }
    __syncthreads();
    const int wave = tid >> 6;
    const int lane = tid & 63;
    for (int n = wave; n < NUM_NOISE; n += 4) {
        const int t = tn_ids[b * NUM_NOISE + n];
        float s = 0.0f;
        for (int d = lane; d < VEC_DIM; d += 64)
            s += xs[d] * O[(size_t)d * NUM_WORDS + t];
#pragma unroll
        for (int off = 32; off > 0; off >>= 1)
            s += __shfl_down(s, off, 64);
        if (lane == 0) out[b * NUM_NOISE + n] = s;
    }
}

extern "C" void kernel_launch(void* const* d_in, const int* in_sizes, int n_in,
                              void* d_out, int out_size, void* d_ws, size_t ws_size,
                              hipStream_t stream) {
    const int*   context_ids = (const int*)  d_in[0];
    const int*   doc_ids     = (const int*)  d_in[1];
    const int*   tn_ids      = (const int*)  d_in[2];
    const float* D           = (const float*)d_in[3];
    const float* W           = (const float*)d_in[4];
    const float* O           = (const float*)d_in[5];
    float*       out         = (float*)d_out;

    const size_t OT_BYTES = (size_t)NUM_WORDS * VEC_DIM * sizeof(float); // 120 MB

    if (ws_size >= OT_BYTES) {
        float* OT = (float*)d_ws;
        dim3 tgrid((NUM_WORDS + TILE - 1) / TILE, (VEC_DIM + TILE - 1) / TILE);
        transpose_kernel<<<tgrid, 256, 0, stream>>>(O, OT);
        pvdm_score_kernel<<<BATCH_N, 256, 0, stream>>>(
            context_ids, doc_ids, tn_ids, D, W, OT, out);
    } else {
        pvdm_score_direct_kernel<<<BATCH_N, 256, 0, stream>>>(
            context_ids, doc_ids, tn_ids, D, W, O, out);
    }
}